// Round 1
// baseline (3152.988 us; speedup 1.0000x reference)
//
#include <hip/hip_runtime.h>

// T2ICrossAttentionPool on MI355X.
// Key identities used (eliminates the (C,I,W,D) wctx tensor entirely):
//   w12[c,i,w]   = sum_r attn[w,r] * Sraw[w,r]          (Sraw = q . img, pre-leaky)
//   |wctx|^2     = attn^T G_i attn,  G_i = imgs_i imgs_i^T  (36x36 Gram)
// Only heavy op: S = Q(15360x1024) * Imgs^T(1024x9216) in bf16 MFMA, fused epilogue.

#define NIMG 256
#define NREG 36
#define NREG_PAD 48
#define DIM 1024
#define NCAP 256
#define MAXW 60
#define WPAD 64

typedef short bf16x8 __attribute__((ext_vector_type(8)));
typedef float f32x4 __attribute__((ext_vector_type(4)));

__device__ __forceinline__ unsigned short f2bf(float f) {
  unsigned u = __float_as_uint(f);
  u += 0x7FFF + ((u >> 16) & 1);   // round-to-nearest-even
  return (unsigned short)(u >> 16);
}

// ---- prep: caps -> masked bf16 q [C][64][D] (zero rows w>=cap_len), w1[c][w]=||q row|| ----
__global__ void k_prep_caps(const float* __restrict__ caps, const int* __restrict__ cap_lens,
                            unsigned short* __restrict__ qbf, float* __restrict__ w1) {
  const int bid = blockIdx.x;          // c*64 + w
  const int c = bid >> 6;
  const int w = bid & 63;
  const int t = threadIdx.x;
  const bool valid = (w < MAXW) && (w < cap_lens[c]);
  float4 v = make_float4(0.f, 0.f, 0.f, 0.f);
  if (valid) v = *reinterpret_cast<const float4*>(caps + ((size_t)c * MAXW + w) * DIM + t * 4);
  ushort4 o;
  o.x = f2bf(v.x); o.y = f2bf(v.y); o.z = f2bf(v.z); o.w = f2bf(v.w);
  *reinterpret_cast<ushort4*>(qbf + (size_t)bid * DIM + t * 4) = o;
  float ss = v.x * v.x + v.y * v.y + v.z * v.z + v.w * v.w;
#pragma unroll
  for (int m = 1; m <= 32; m <<= 1) ss += __shfl_xor(ss, m);
  __shared__ float part[4];
  if ((t & 63) == 0) part[t >> 6] = ss;
  __syncthreads();
  if (t == 0) w1[bid] = sqrtf(part[0] + part[1] + part[2] + part[3]);
}

// ---- prep: imgs -> bf16 [I][48][D], rows 36..47 zero ----
__global__ void k_prep_imgs(const float* __restrict__ imgs, unsigned short* __restrict__ ibf) {
  const int bid = blockIdx.x;          // i*48 + r
  const int i = bid / NREG_PAD;
  const int r = bid - i * NREG_PAD;
  const int t = threadIdx.x;
  float4 v = make_float4(0.f, 0.f, 0.f, 0.f);
  if (r < NREG) v = *reinterpret_cast<const float4*>(imgs + ((size_t)i * NREG + r) * DIM + t * 4);
  ushort4 o;
  o.x = f2bf(v.x); o.y = f2bf(v.y); o.z = f2bf(v.z); o.w = f2bf(v.w);
  *reinterpret_cast<ushort4*>(ibf + (size_t)bid * DIM + t * 4) = o;
}

// ---- prep: Gram G_i[r][r'] fp32, one block per image ----
__device__ __forceinline__ void pairDecode(int p, int& r, int& c) {
  r = 0;
  while (p >= NREG - r) { p -= NREG - r; ++r; }
  c = r + p;
}

__global__ void k_gram(const float* __restrict__ imgs, float* __restrict__ gram) {
  __shared__ float tile[NREG * 129];   // +1 pad: bank spread
  const int i = blockIdx.x;
  const int t = threadIdx.x;
  const int NP = NREG * (NREG + 1) / 2;   // 666 upper-tri pairs
  int r0 = 0, q0 = 0, r1 = 0, q1 = 0, r2 = 0, q2 = 0;
  const bool v0 = (t < NP), v1 = (t + 256 < NP), v2 = (t + 512 < NP);
  if (v0) pairDecode(t, r0, q0);
  if (v1) pairDecode(t + 256, r1, q1);
  if (v2) pairDecode(t + 512, r2, q2);
  float s0 = 0.f, s1 = 0.f, s2 = 0.f;
  for (int kk = 0; kk < DIM; kk += 128) {
    __syncthreads();
    for (int idx = t; idx < NREG * 128; idx += 256) {
      int r = idx >> 7, k = idx & 127;
      tile[r * 129 + k] = imgs[((size_t)i * NREG + r) * DIM + kk + k];
    }
    __syncthreads();
    for (int k = 0; k < 128; ++k) {
      if (v0) s0 += tile[r0 * 129 + k] * tile[q0 * 129 + k];
      if (v1) s1 += tile[r1 * 129 + k] * tile[q1 * 129 + k];
      if (v2) s2 += tile[r2 * 129 + k] * tile[q2 * 129 + k];
    }
  }
  float* g = gram + (size_t)i * (NREG * NREG);
  if (v0) { g[r0 * NREG + q0] = s0; g[q0 * NREG + r0] = s0; }
  if (v1) { g[r1 * NREG + q1] = s1; g[q1 * NREG + r1] = s1; }
  if (v2) { g[r2 * NREG + q2] = s2; g[q2 * NREG + r2] = s2; }
}

// ---- main fused kernel ----
// Grid: (I/4, C/2). Block 256 = 4 waves in 2x2: wave(wy,wx) -> caption c0+wy, images i0+wx*2+{0,1}.
// Per-wave S tile: M=64 (one caption, W padded), N=96 (2 images x 48 padded R), K=1024.
#define BK 64
#define LDK 72   // +8 halves pad -> conflict-light ds_read_b128

union MainLds {
  struct { unsigned short A[128 * LDK]; unsigned short B[192 * LDK]; } st;  // 46080 B
  struct { _Float16 attn[4][64][50]; float w12[4][64]; float gram[4][NREG * NREG]; } ep;  // 47360 B
};

__launch_bounds__(256, 2)
__global__ void k_main(const unsigned short* __restrict__ qbf,
                       const unsigned short* __restrict__ ibf,
                       const float* __restrict__ w1,
                       const float* __restrict__ gram,
                       const int* __restrict__ cap_lens,
                       float* __restrict__ out) {
  __shared__ MainLds lds;
  const int tid = threadIdx.x;
  const int lane = tid & 63;
  const int l15 = lane & 15;
  const int quad = lane >> 4;
  const int wv = tid >> 6;
  const int wy = wv >> 1;
  const int wx = wv & 1;
  const int i0 = blockIdx.x * 4;
  const int c0 = blockIdx.y * 2;
  const int c = c0 + wy;
  const int clen = cap_lens[c];

  f32x4 acc[4][6];
  const f32x4 zero4 = {0.f, 0.f, 0.f, 0.f};
#pragma unroll
  for (int mt = 0; mt < 4; ++mt)
#pragma unroll
    for (int nt = 0; nt < 6; ++nt) acc[mt][nt] = zero4;

  const int aRow = wy * 64;
  const int bRow = wx * 96;

  for (int kk = 0; kk < DIM; kk += BK) {
    // stage A: 128 rows x 64 halves (q rows are contiguous: global row = c0*64 + m)
#pragma unroll
    for (int j = 0; j < 4; ++j) {
      int idx = tid + j * 256;            // 0..1023 uint4 units
      int m = idx >> 3;
      int ku = (idx & 7) << 3;
      uint4 v = *reinterpret_cast<const uint4*>(qbf + ((size_t)(c0 * 64 + m)) * DIM + kk + ku);
      *reinterpret_cast<uint4*>(&lds.st.A[m * LDK + ku]) = v;
    }
    // stage B: 192 rows x 64 halves (img rows contiguous: global row = i0*48 + n)
#pragma unroll
    for (int j = 0; j < 6; ++j) {
      int idx = tid + j * 256;            // 0..1535
      int n = idx >> 3;
      int ku = (idx & 7) << 3;
      uint4 v = *reinterpret_cast<const uint4*>(ibf + ((size_t)(i0 * NREG_PAD + n)) * DIM + kk + ku);
      *reinterpret_cast<uint4*>(&lds.st.B[n * LDK + ku]) = v;
    }
    __syncthreads();
#pragma unroll
    for (int ks = 0; ks < 2; ++ks) {
      const int kb = ks * 32 + quad * 8;
      bf16x8 fa[4], fb[6];
#pragma unroll
      for (int mt = 0; mt < 4; ++mt)
        fa[mt] = *reinterpret_cast<const bf16x8*>(&lds.st.A[(aRow + mt * 16 + l15) * LDK + kb]);
#pragma unroll
      for (int nt = 0; nt < 6; ++nt)
        fb[nt] = *reinterpret_cast<const bf16x8*>(&lds.st.B[(bRow + nt * 16 + l15) * LDK + kb]);
#pragma unroll
      for (int mt = 0; mt < 4; ++mt)
#pragma unroll
        for (int nt = 0; nt < 6; ++nt)
          acc[mt][nt] = __builtin_amdgcn_mfma_f32_16x16x32_bf16(fa[mt], fb[nt], acc[mt][nt], 0, 0, 0);
    }
    __syncthreads();
  }

  // ---- epilogue ----
  // load Gram for the 4 images of this WG
  for (int idx = tid; idx < 4 * NREG * NREG; idx += 256) {
    int gi = idx / (NREG * NREG);
    int rr = idx - gi * (NREG * NREG);
    lds.ep.gram[gi][rr] = gram[(size_t)(i0 + gi) * (NREG * NREG) + rr];
  }
  __syncthreads();

  for (int img = 0; img < 2; ++img) {
    // per-region l2 norm over w (C-layout: rows live across quads -> xor 16,32)
    float scale[3];
#pragma unroll
    for (int nt3 = 0; nt3 < 3; ++nt3) {
      const int nt = img * 3 + nt3;
      float p = 0.f;
#pragma unroll
      for (int mt = 0; mt < 4; ++mt)
#pragma unroll
        for (int rg = 0; rg < 4; ++rg) {
          float s = acc[mt][nt][rg];
          float l = s < 0.f ? 0.1f * s : s;
          p += l * l;
        }
      p += __shfl_xor(p, 16);
      p += __shfl_xor(p, 32);
      scale[nt3] = 9.0f / (sqrtf(p) + 1e-8f);   // SMOOTH folded in
    }
    const bool vr2 = (l15 < 4);   // nt3==2 covers r=32..47; valid only r<36
    // softmax over r (cols live across the 16 lanes of a quad -> xor 1..8), w12, attn->LDS
#pragma unroll
    for (int mt = 0; mt < 4; ++mt) {
#pragma unroll
      for (int rg = 0; rg < 4; ++rg) {
        const float s0 = acc[mt][img * 3 + 0][rg];
        const float s1 = acc[mt][img * 3 + 1][rg];
        const float s2 = acc[mt][img * 3 + 2][rg];
        const float t0 = (s0 < 0.f ? 0.1f * s0 : s0) * scale[0];
        const float t1 = (s1 < 0.f ? 0.1f * s1 : s1) * scale[1];
        const float t2 = (s2 < 0.f ? 0.1f * s2 : s2) * scale[2];
        float mx = fmaxf(t0, t1);
        if (vr2) mx = fmaxf(mx, t2);
        mx = fmaxf(mx, __shfl_xor(mx, 1));
        mx = fmaxf(mx, __shfl_xor(mx, 2));
        mx = fmaxf(mx, __shfl_xor(mx, 4));
        mx = fmaxf(mx, __shfl_xor(mx, 8));
        const float e0 = __expf(t0 - mx);
        const float e1 = __expf(t1 - mx);
        const float e2 = vr2 ? __expf(t2 - mx) : 0.f;
        float sm = e0 + e1 + e2;
        sm += __shfl_xor(sm, 1);
        sm += __shfl_xor(sm, 2);
        sm += __shfl_xor(sm, 4);
        sm += __shfl_xor(sm, 8);
        const float inv = 1.0f / sm;
        const float a0 = e0 * inv, a1 = e1 * inv, a2 = e2 * inv;
        float wp = a0 * s0 + a1 * s1 + (vr2 ? a2 * s2 : 0.f);   // w12 uses RAW s
        wp += __shfl_xor(wp, 1);
        wp += __shfl_xor(wp, 2);
        wp += __shfl_xor(wp, 4);
        wp += __shfl_xor(wp, 8);
        const int w = mt * 16 + quad * 4 + rg;
        lds.ep.attn[wv][w][l15] = (_Float16)a0;
        lds.ep.attn[wv][w][16 + l15] = (_Float16)a1;
        if (vr2) lds.ep.attn[wv][w][32 + l15] = (_Float16)a2;
        if (l15 == 0) lds.ep.w12[wv][w] = wp;
      }
    }
    __syncthreads();
    // w2^2 = attn^T G attn (triangle), sim, masked mean
    float simv = 0.f;
    if (lane < clen) {
      const _Float16* arow = lds.ep.attn[wv][lane];
      const float* G = lds.ep.gram[wx * 2 + img];
      float qsum = 0.f;
      for (int r = 0; r < NREG; ++r) {
        const float ar = (float)arow[r];
        float partial = 0.5f * ar * G[r * NREG + r];
        for (int r2 = r + 1; r2 < NREG; ++r2)
          partial += (float)arow[r2] * G[r * NREG + r2];
        qsum += ar * partial;
      }
      const float w2v = sqrtf(2.0f * qsum);
      const float w12v = lds.ep.w12[wv][lane];
      const float w1v = w1[(size_t)c * WPAD + lane];
      simv = w12v / fmaxf(w1v * w2v, 1e-8f);
    }
    simv += __shfl_xor(simv, 1);
    simv += __shfl_xor(simv, 2);
    simv += __shfl_xor(simv, 4);
    simv += __shfl_xor(simv, 8);
    simv += __shfl_xor(simv, 16);
    simv += __shfl_xor(simv, 32);
    if (lane == 0) {
      const int i = i0 + wx * 2 + img;
      out[(size_t)i * NCAP + c] = simv / (float)clen;
    }
    __syncthreads();
  }
}

extern "C" void kernel_launch(void* const* d_in, const int* in_sizes, int n_in,
                              void* d_out, int out_size, void* d_ws, size_t ws_size,
                              hipStream_t stream) {
  const float* imgs = (const float*)d_in[0];
  const float* caps = (const float*)d_in[1];
  const int* cap_lens = (const int*)d_in[3];   // img_lens (d_in[2]) unused by reference
  float* out = (float*)d_out;

  char* ws = (char*)d_ws;
  const size_t QBF_B = (size_t)NCAP * WPAD * DIM * 2;        // 33,554,432
  const size_t IBF_B = (size_t)NIMG * NREG_PAD * DIM * 2;    // 25,165,824
  const size_t W1_B = (size_t)NCAP * WPAD * 4;               // 65,536
  unsigned short* qbf = (unsigned short*)ws;
  unsigned short* ibf = (unsigned short*)(ws + QBF_B);
  float* w1 = (float*)(ws + QBF_B + IBF_B);
  float* gram = (float*)(ws + QBF_B + IBF_B + W1_B);         // 1,327,104 -> total ~60.1 MB

  k_prep_caps<<<NCAP * WPAD, 256, 0, stream>>>(caps, cap_lens, qbf, w1);
  k_prep_imgs<<<NIMG * NREG_PAD, 256, 0, stream>>>(imgs, ibf);
  k_gram<<<NIMG, 256, 0, stream>>>(imgs, gram);
  k_main<<<dim3(NIMG / 4, NCAP / 2), 256, 0, stream>>>(qbf, ibf, w1, gram, cap_lens, out);
}

// Round 2
// 1986.237 us; speedup vs baseline: 1.5874x; 1.5874x over previous
//
#include <hip/hip_runtime.h>

// T2ICrossAttentionPool on MI355X.
// Key identities used (eliminates the (C,I,W,D) wctx tensor entirely):
//   w12[c,i,w]   = sum_r attn[w,r] * Sraw[w,r]          (Sraw = q . img, pre-leaky)
//   |wctx|^2     = attn^T G_i attn,  G_i = imgs_i imgs_i^T  (36x36 Gram)
// Only heavy op: S = Q(16384x1024) * Imgs^T(1024x12288) in bf16 MFMA, fused epilogue.
//
// R1 fix: epilogue img-loop is now #pragma unroll — previously acc[mt][img*3+nt3]
// was dynamically indexed, forcing the 96-VGPR accumulator to scratch (12.5 GB of
// HBM writes, the R1 bottleneck). Also: XOR-16B-unit swizzle on LDS tiles (the
// LDK=72 pad gave 8-way ds_read_b128 bank conflicts, 3.8e8 conflict cycles).

#define NIMG 256
#define NREG 36
#define NREG_PAD 48
#define DIM 1024
#define NCAP 256
#define MAXW 60
#define WPAD 64

typedef short bf16x8 __attribute__((ext_vector_type(8)));
typedef float f32x4 __attribute__((ext_vector_type(4)));

__device__ __forceinline__ unsigned short f2bf(float f) {
  unsigned u = __float_as_uint(f);
  u += 0x7FFF + ((u >> 16) & 1);   // round-to-nearest-even
  return (unsigned short)(u >> 16);
}

// ---- prep: caps -> masked bf16 q [C][64][D] (zero rows w>=cap_len), w1[c][w]=||q row|| ----
__global__ void k_prep_caps(const float* __restrict__ caps, const int* __restrict__ cap_lens,
                            unsigned short* __restrict__ qbf, float* __restrict__ w1) {
  const int bid = blockIdx.x;          // c*64 + w
  const int c = bid >> 6;
  const int w = bid & 63;
  const int t = threadIdx.x;
  const bool valid = (w < MAXW) && (w < cap_lens[c]);
  float4 v = make_float4(0.f, 0.f, 0.f, 0.f);
  if (valid) v = *reinterpret_cast<const float4*>(caps + ((size_t)c * MAXW + w) * DIM + t * 4);
  ushort4 o;
  o.x = f2bf(v.x); o.y = f2bf(v.y); o.z = f2bf(v.z); o.w = f2bf(v.w);
  *reinterpret_cast<ushort4*>(qbf + (size_t)bid * DIM + t * 4) = o;
  float ss = v.x * v.x + v.y * v.y + v.z * v.z + v.w * v.w;
#pragma unroll
  for (int m = 1; m <= 32; m <<= 1) ss += __shfl_xor(ss, m);
  __shared__ float part[4];
  if ((t & 63) == 0) part[t >> 6] = ss;
  __syncthreads();
  if (t == 0) w1[bid] = sqrtf(part[0] + part[1] + part[2] + part[3]);
}

// ---- prep: imgs -> bf16 [I][48][D], rows 36..47 zero ----
__global__ void k_prep_imgs(const float* __restrict__ imgs, unsigned short* __restrict__ ibf) {
  const int bid = blockIdx.x;          // i*48 + r
  const int i = bid / NREG_PAD;
  const int r = bid - i * NREG_PAD;
  const int t = threadIdx.x;
  float4 v = make_float4(0.f, 0.f, 0.f, 0.f);
  if (r < NREG) v = *reinterpret_cast<const float4*>(imgs + ((size_t)i * NREG + r) * DIM + t * 4);
  ushort4 o;
  o.x = f2bf(v.x); o.y = f2bf(v.y); o.z = f2bf(v.z); o.w = f2bf(v.w);
  *reinterpret_cast<ushort4*>(ibf + (size_t)bid * DIM + t * 4) = o;
}

// ---- prep: Gram G_i[r][r'] fp32, one block per image ----
__device__ __forceinline__ void pairDecode(int p, int& r, int& c) {
  r = 0;
  while (p >= NREG - r) { p -= NREG - r; ++r; }
  c = r + p;
}

__global__ void k_gram(const float* __restrict__ imgs, float* __restrict__ gram) {
  __shared__ float tile[NREG * 129];   // +1 pad: bank spread
  const int i = blockIdx.x;
  const int t = threadIdx.x;
  const int NP = NREG * (NREG + 1) / 2;   // 666 upper-tri pairs
  int r0 = 0, q0 = 0, r1 = 0, q1 = 0, r2 = 0, q2 = 0;
  const bool v0 = (t < NP), v1 = (t + 256 < NP), v2 = (t + 512 < NP);
  if (v0) pairDecode(t, r0, q0);
  if (v1) pairDecode(t + 256, r1, q1);
  if (v2) pairDecode(t + 512, r2, q2);
  float s0 = 0.f, s1 = 0.f, s2 = 0.f;
  for (int kk = 0; kk < DIM; kk += 128) {
    __syncthreads();
    for (int idx = t; idx < NREG * 128; idx += 256) {
      int r = idx >> 7, k = idx & 127;
      tile[r * 129 + k] = imgs[((size_t)i * NREG + r) * DIM + kk + k];
    }
    __syncthreads();
    for (int k = 0; k < 128; ++k) {
      if (v0) s0 += tile[r0 * 129 + k] * tile[q0 * 129 + k];
      if (v1) s1 += tile[r1 * 129 + k] * tile[q1 * 129 + k];
      if (v2) s2 += tile[r2 * 129 + k] * tile[q2 * 129 + k];
    }
  }
  float* g = gram + (size_t)i * (NREG * NREG);
  if (v0) { g[r0 * NREG + q0] = s0; g[q0 * NREG + r0] = s0; }
  if (v1) { g[r1 * NREG + q1] = s1; g[q1 * NREG + r1] = s1; }
  if (v2) { g[r2 * NREG + q2] = s2; g[q2 * NREG + r2] = s2; }
}

// ---- main fused kernel ----
// Grid: (I/4, C/2). Block 256 = 4 waves in 2x2: wave(wy,wx) -> caption c0+wy, images i0+wx*2+{0,1}.
// Per-wave S tile: M=64 (one caption, W padded), N=96 (2 images x 48 padded R), K=1024.
// LDS tiles use XOR swizzle: 16B unit u of row m stored at physical unit (u ^ (m&7)).
// -> staging writes and ds_read_b128 fragment reads are both bank-conflict-free.
#define BK 64

union MainLds {
  struct { unsigned short A[128 * 64]; unsigned short B[192 * 64]; } st;  // 40960 B
  struct { _Float16 attn[4][64][50]; float w12[4][64]; float gram[4][NREG * NREG]; } ep;  // 47360 B
};

__launch_bounds__(256, 2)
__global__ void k_main(const unsigned short* __restrict__ qbf,
                       const unsigned short* __restrict__ ibf,
                       const float* __restrict__ w1,
                       const float* __restrict__ gram,
                       const int* __restrict__ cap_lens,
                       float* __restrict__ out) {
  __shared__ MainLds lds;
  const int tid = threadIdx.x;
  const int lane = tid & 63;
  const int l15 = lane & 15;
  const int quad = lane >> 4;
  const int wv = tid >> 6;
  const int wy = wv >> 1;
  const int wx = wv & 1;
  const int i0 = blockIdx.x * 4;
  const int c0 = blockIdx.y * 2;
  const int c = c0 + wy;
  const int clen = cap_lens[c];

  f32x4 acc[4][6];
  const f32x4 zero4 = {0.f, 0.f, 0.f, 0.f};
#pragma unroll
  for (int mt = 0; mt < 4; ++mt)
#pragma unroll
    for (int nt = 0; nt < 6; ++nt) acc[mt][nt] = zero4;

  const int aRow = wy * 64;
  const int bRow = wx * 96;

  for (int kk = 0; kk < DIM; kk += BK) {
    // stage A: 128 rows x 64 halves (q rows contiguous: global row = c0*64 + m)
#pragma unroll
    for (int j = 0; j < 4; ++j) {
      int idx = tid + j * 256;            // 0..1023 uint4 units
      int m = idx >> 3;
      int u = idx & 7;
      uint4 v = *reinterpret_cast<const uint4*>(qbf + ((size_t)(c0 * 64 + m)) * DIM + kk + (u << 3));
      *reinterpret_cast<uint4*>(&lds.st.A[m * 64 + ((u ^ (m & 7)) << 3)]) = v;
    }
    // stage B: 192 rows x 64 halves (img rows contiguous: global row = i0*48 + n)
#pragma unroll
    for (int j = 0; j < 6; ++j) {
      int idx = tid + j * 256;            // 0..1535
      int n = idx >> 3;
      int u = idx & 7;
      uint4 v = *reinterpret_cast<const uint4*>(ibf + ((size_t)(i0 * NREG_PAD + n)) * DIM + kk + (u << 3));
      *reinterpret_cast<uint4*>(&lds.st.B[n * 64 + ((u ^ (n & 7)) << 3)]) = v;
    }
    __syncthreads();
#pragma unroll
    for (int ks = 0; ks < 2; ++ks) {
      const int ub = ks * 4 + quad;       // logical 16B-unit index within the row
      bf16x8 fa[4], fb[6];
#pragma unroll
      for (int mt = 0; mt < 4; ++mt) {
        const int r = aRow + mt * 16 + l15;
        fa[mt] = *reinterpret_cast<const bf16x8*>(&lds.st.A[r * 64 + ((ub ^ (r & 7)) << 3)]);
      }
#pragma unroll
      for (int nt = 0; nt < 6; ++nt) {
        const int r = bRow + nt * 16 + l15;
        fb[nt] = *reinterpret_cast<const bf16x8*>(&lds.st.B[r * 64 + ((ub ^ (r & 7)) << 3)]);
      }
#pragma unroll
      for (int mt = 0; mt < 4; ++mt)
#pragma unroll
        for (int nt = 0; nt < 6; ++nt)
          acc[mt][nt] = __builtin_amdgcn_mfma_f32_16x16x32_bf16(fa[mt], fb[nt], acc[mt][nt], 0, 0, 0);
    }
    __syncthreads();
  }

  // ---- epilogue ----
  // load Gram for the 4 images of this WG
  for (int idx = tid; idx < 4 * NREG * NREG; idx += 256) {
    int gi = idx / (NREG * NREG);
    int rr = idx - gi * (NREG * NREG);
    lds.ep.gram[gi][rr] = gram[(size_t)(i0 + gi) * (NREG * NREG) + rr];
  }
  __syncthreads();

#pragma unroll
  for (int img = 0; img < 2; ++img) {
    // per-region l2 norm over w (C-layout: rows live across quads -> xor 16,32)
    float scale[3];
#pragma unroll
    for (int nt3 = 0; nt3 < 3; ++nt3) {
      const int nt = img * 3 + nt3;
      float p = 0.f;
#pragma unroll
      for (int mt = 0; mt < 4; ++mt)
#pragma unroll
        for (int rg = 0; rg < 4; ++rg) {
          float s = acc[mt][nt][rg];
          float l = s < 0.f ? 0.1f * s : s;
          p += l * l;
        }
      p += __shfl_xor(p, 16);
      p += __shfl_xor(p, 32);
      scale[nt3] = 9.0f / (sqrtf(p) + 1e-8f);   // SMOOTH folded in
    }
    const bool vr2 = (l15 < 4);   // nt3==2 covers r=32..47; valid only r<36
    // softmax over r (cols live across the 16 lanes of a quad -> xor 1..8), w12, attn->LDS
#pragma unroll
    for (int mt = 0; mt < 4; ++mt) {
#pragma unroll
      for (int rg = 0; rg < 4; ++rg) {
        const float s0 = acc[mt][img * 3 + 0][rg];
        const float s1 = acc[mt][img * 3 + 1][rg];
        const float s2 = acc[mt][img * 3 + 2][rg];
        const float t0 = (s0 < 0.f ? 0.1f * s0 : s0) * scale[0];
        const float t1 = (s1 < 0.f ? 0.1f * s1 : s1) * scale[1];
        const float t2 = (s2 < 0.f ? 0.1f * s2 : s2) * scale[2];
        float mx = fmaxf(t0, t1);
        if (vr2) mx = fmaxf(mx, t2);
        mx = fmaxf(mx, __shfl_xor(mx, 1));
        mx = fmaxf(mx, __shfl_xor(mx, 2));
        mx = fmaxf(mx, __shfl_xor(mx, 4));
        mx = fmaxf(mx, __shfl_xor(mx, 8));
        const float e0 = __expf(t0 - mx);
        const float e1 = __expf(t1 - mx);
        const float e2 = vr2 ? __expf(t2 - mx) : 0.f;
        float sm = e0 + e1 + e2;
        sm += __shfl_xor(sm, 1);
        sm += __shfl_xor(sm, 2);
        sm += __shfl_xor(sm, 4);
        sm += __shfl_xor(sm, 8);
        const float inv = 1.0f / sm;
        const float a0 = e0 * inv, a1 = e1 * inv, a2 = e2 * inv;
        float wp = a0 * s0 + a1 * s1 + (vr2 ? a2 * s2 : 0.f);   // w12 uses RAW s
        wp += __shfl_xor(wp, 1);
        wp += __shfl_xor(wp, 2);
        wp += __shfl_xor(wp, 4);
        wp += __shfl_xor(wp, 8);
        const int w = mt * 16 + quad * 4 + rg;
        lds.ep.attn[wv][w][l15] = (_Float16)a0;
        lds.ep.attn[wv][w][16 + l15] = (_Float16)a1;
        if (vr2) lds.ep.attn[wv][w][32 + l15] = (_Float16)a2;
        if (l15 == 0) lds.ep.w12[wv][w] = wp;
      }
    }
    // attn/w12 are wave-private (indexed by wv): no __syncthreads needed,
    // in-wave lgkmcnt ordering suffices.
    float simv = 0.f;
    if (lane < clen) {
      const _Float16* arow = lds.ep.attn[wv][lane];
      const float* G = lds.ep.gram[wx * 2 + img];
      float qsum = 0.f;
      for (int r = 0; r < NREG; ++r) {
        const float ar = (float)arow[r];
        float partial = 0.5f * ar * G[r * NREG + r];
        for (int r2 = r + 1; r2 < NREG; ++r2)
          partial += (float)arow[r2] * G[r * NREG + r2];
        qsum += ar * partial;
      }
      const float w2v = sqrtf(2.0f * qsum);
      const float w12v = lds.ep.w12[wv][lane];
      const float w1v = w1[(size_t)c * WPAD + lane];
      simv = w12v / fmaxf(w1v * w2v, 1e-8f);
    }
    simv += __shfl_xor(simv, 1);
    simv += __shfl_xor(simv, 2);
    simv += __shfl_xor(simv, 4);
    simv += __shfl_xor(simv, 8);
    simv += __shfl_xor(simv, 16);
    simv += __shfl_xor(simv, 32);
    if (lane == 0) {
      const int i = i0 + wx * 2 + img;
      out[(size_t)i * NCAP + c] = simv / (float)clen;
    }
  }
}

extern "C" void kernel_launch(void* const* d_in, const int* in_sizes, int n_in,
                              void* d_out, int out_size, void* d_ws, size_t ws_size,
                              hipStream_t stream) {
  const float* imgs = (const float*)d_in[0];
  const float* caps = (const float*)d_in[1];
  const int* cap_lens = (const int*)d_in[3];   // img_lens (d_in[2]) unused by reference
  float* out = (float*)d_out;

  char* ws = (char*)d_ws;
  const size_t QBF_B = (size_t)NCAP * WPAD * DIM * 2;        // 33,554,432
  const size_t IBF_B = (size_t)NIMG * NREG_PAD * DIM * 2;    // 25,165,824
  const size_t W1_B = (size_t)NCAP * WPAD * 4;               // 65,536
  unsigned short* qbf = (unsigned short*)ws;
  unsigned short* ibf = (unsigned short*)(ws + QBF_B);
  float* w1 = (float*)(ws + QBF_B + IBF_B);
  float* gram = (float*)(ws + QBF_B + IBF_B + W1_B);         // 1,327,104 -> total ~60.1 MB

  k_prep_caps<<<NCAP * WPAD, 256, 0, stream>>>(caps, cap_lens, qbf, w1);
  k_prep_imgs<<<NIMG * NREG_PAD, 256, 0, stream>>>(imgs, ibf);
  k_gram<<<NIMG, 256, 0, stream>>>(imgs, gram);
  k_main<<<dim3(NIMG / 4, NCAP / 2), 256, 0, stream>>>(qbf, ibf, w1, gram, cap_lens, out);
}

// Round 3
// 1613.634 us; speedup vs baseline: 1.9540x; 1.2309x over previous
//
#include <hip/hip_runtime.h>

// T2ICrossAttentionPool on MI355X.
// Identities: w12[c,i,w] = sum_r attn*Sraw;  |wctx|^2 = a^T G a with
//   G split as exact fp32 diagonal (register math) + off-diag G' in bf16 (MFMA):
//   w2^2 = sum_r a_r^2 diag_r  +  a^T G' a,  Y = Attn x G' via mfma_16x16x32_bf16.
// R2 finding: SQ_LDS_BANK_CONFLICT identical across layouts -> epilogue scalar
// Gram loop (~2700 ds_read_u16/wave) was the bottleneck, not the K-loop. This
// round replaces it with 48 MFMAs/wave + ~100 vector LDS ops.

#define NIMG 256
#define NREG 36
#define NREG_PAD 48
#define DIM 1024
#define NCAP 256
#define MAXW 60
#define WPAD 64

typedef short bf16x8 __attribute__((ext_vector_type(8)));
typedef float f32x4 __attribute__((ext_vector_type(4)));

__device__ __forceinline__ unsigned short f2bf(float f) {
  unsigned u = __float_as_uint(f);
  u += 0x7FFF + ((u >> 16) & 1);   // round-to-nearest-even
  return (unsigned short)(u >> 16);
}

// ---- prep: caps -> masked bf16 q [C][64][D] (zero rows w>=cap_len), w1[c][w]=||q row|| ----
__global__ void k_prep_caps(const float* __restrict__ caps, const int* __restrict__ cap_lens,
                            unsigned short* __restrict__ qbf, float* __restrict__ w1) {
  const int bid = blockIdx.x;          // c*64 + w
  const int c = bid >> 6;
  const int w = bid & 63;
  const int t = threadIdx.x;
  const bool valid = (w < MAXW) && (w < cap_lens[c]);
  float4 v = make_float4(0.f, 0.f, 0.f, 0.f);
  if (valid) v = *reinterpret_cast<const float4*>(caps + ((size_t)c * MAXW + w) * DIM + t * 4);
  ushort4 o;
  o.x = f2bf(v.x); o.y = f2bf(v.y); o.z = f2bf(v.z); o.w = f2bf(v.w);
  *reinterpret_cast<ushort4*>(qbf + (size_t)bid * DIM + t * 4) = o;
  float ss = v.x * v.x + v.y * v.y + v.z * v.z + v.w * v.w;
#pragma unroll
  for (int m = 1; m <= 32; m <<= 1) ss += __shfl_xor(ss, m);
  __shared__ float part[4];
  if ((t & 63) == 0) part[t >> 6] = ss;
  __syncthreads();
  if (t == 0) w1[bid] = sqrtf(part[0] + part[1] + part[2] + part[3]);
}

// ---- prep: imgs -> bf16 [I][48][D], rows 36..47 zero ----
__global__ void k_prep_imgs(const float* __restrict__ imgs, unsigned short* __restrict__ ibf) {
  const int bid = blockIdx.x;          // i*48 + r
  const int i = bid / NREG_PAD;
  const int r = bid - i * NREG_PAD;
  const int t = threadIdx.x;
  float4 v = make_float4(0.f, 0.f, 0.f, 0.f);
  if (r < NREG) v = *reinterpret_cast<const float4*>(imgs + ((size_t)i * NREG + r) * DIM + t * 4);
  ushort4 o;
  o.x = f2bf(v.x); o.y = f2bf(v.y); o.z = f2bf(v.z); o.w = f2bf(v.w);
  *reinterpret_cast<ushort4*>(ibf + (size_t)bid * DIM + t * 4) = o;
}

// ---- prep: Gram -> off-diag bf16 G'[i][48][64] (rows/cols>=36 and diag zero) + fp32 diag[i][48] ----
__device__ __forceinline__ void pairDecode(int p, int& r, int& c) {
  r = 0;
  while (p >= NREG - r) { p -= NREG - r; ++r; }
  c = r + p;
}

__global__ void k_gram(const float* __restrict__ imgs, unsigned short* __restrict__ gbf,
                       float* __restrict__ gdiag) {
  __shared__ float tile[NREG * 129];
  const int i = blockIdx.x;
  const int t = threadIdx.x;
  unsigned short* g = gbf + (size_t)i * (48 * 64);
  // zero exactly the entries the pair phase does NOT write (no race, no barrier needed)
  for (int idx = t; idx < 48 * 64; idx += 256) {
    int rr = idx >> 6, cc = idx & 63;
    if (rr >= NREG || cc >= NREG || rr == cc) g[idx] = 0;
  }
  if (t >= NREG && t < 48) gdiag[(size_t)i * 48 + t] = 0.f;

  const int NP = NREG * (NREG + 1) / 2;   // 666 pairs (incl. diag)
  int r0 = 0, q0 = 0, r1 = 0, q1 = 0, r2 = 0, q2 = 0;
  const bool v0 = (t < NP), v1 = (t + 256 < NP), v2 = (t + 512 < NP);
  if (v0) pairDecode(t, r0, q0);
  if (v1) pairDecode(t + 256, r1, q1);
  if (v2) pairDecode(t + 512, r2, q2);
  float s0 = 0.f, s1 = 0.f, s2 = 0.f;
  for (int kk = 0; kk < DIM; kk += 128) {
    __syncthreads();
    for (int idx = t; idx < NREG * 128; idx += 256) {
      int r = idx >> 7, k = idx & 127;
      tile[r * 129 + k] = imgs[((size_t)i * NREG + r) * DIM + kk + k];
    }
    __syncthreads();
    for (int k = 0; k < 128; ++k) {
      if (v0) s0 += tile[r0 * 129 + k] * tile[q0 * 129 + k];
      if (v1) s1 += tile[r1 * 129 + k] * tile[q1 * 129 + k];
      if (v2) s2 += tile[r2 * 129 + k] * tile[q2 * 129 + k];
    }
  }
  float* d = gdiag + (size_t)i * 48;
  if (v0) { if (r0 == q0) d[r0] = s0; else { unsigned short b = f2bf(s0); g[r0 * 64 + q0] = b; g[q0 * 64 + r0] = b; } }
  if (v1) { if (r1 == q1) d[r1] = s1; else { unsigned short b = f2bf(s1); g[r1 * 64 + q1] = b; g[q1 * 64 + r1] = b; } }
  if (v2) { if (r2 == q2) d[r2] = s2; else { unsigned short b = f2bf(s2); g[r2 * 64 + q2] = b; g[q2 * 64 + r2] = b; } }
}

// ---- main fused kernel ----
// Grid: (I/4, C/2). Block 256 = 4 waves in 2x2: wave(wy,wx) -> caption c0+wy, images i0+wx*2+{0,1}.
// Per-wave S tile: M=64 (one caption, W padded), N=96 (2 images x 48 padded R), K=1024.
// All LDS 2D tiles use XOR swizzle: 16B unit u of row m stored at physical unit (u ^ (m&7)).
#define BK 64

union MainLds {
  struct { unsigned short A[128 * 64]; unsigned short B[192 * 64]; } st;  // 40960 B
  struct {
    unsigned short gp[4][48 * 64];    // G' bf16, swizzled, per image      24576 B
    unsigned short attn[4][64 * 64];  // attn bf16 rows [w][64], swizzled  32768 B
    float w12[4][64];
    float w2d[4][64];
    float w2x[4][64];                 //                                     3072 B
  } ep;                               // total 60416 B
};

__launch_bounds__(256, 2)
__global__ void k_main(const unsigned short* __restrict__ qbf,
                       const unsigned short* __restrict__ ibf,
                       const float* __restrict__ w1,
                       const unsigned short* __restrict__ gbf,
                       const float* __restrict__ gdiag,
                       const int* __restrict__ cap_lens,
                       float* __restrict__ out) {
  __shared__ MainLds lds;
  const int tid = threadIdx.x;
  const int lane = tid & 63;
  const int l15 = lane & 15;
  const int quad = lane >> 4;
  const int wv = tid >> 6;
  const int wy = wv >> 1;
  const int wx = wv & 1;
  const int i0 = blockIdx.x * 4;
  const int c0 = blockIdx.y * 2;
  const int c = c0 + wy;
  const int clen = cap_lens[c];

  f32x4 acc[4][6];
  const f32x4 zero4 = {0.f, 0.f, 0.f, 0.f};
#pragma unroll
  for (int mt = 0; mt < 4; ++mt)
#pragma unroll
    for (int nt = 0; nt < 6; ++nt) acc[mt][nt] = zero4;

  const int aRow = wy * 64;
  const int bRow = wx * 96;

  for (int kk = 0; kk < DIM; kk += BK) {
#pragma unroll
    for (int j = 0; j < 4; ++j) {
      int idx = tid + j * 256;            // 0..1023 uint4 units
      int m = idx >> 3;
      int u = idx & 7;
      uint4 v = *reinterpret_cast<const uint4*>(qbf + ((size_t)(c0 * 64 + m)) * DIM + kk + (u << 3));
      *reinterpret_cast<uint4*>(&lds.st.A[m * 64 + ((u ^ (m & 7)) << 3)]) = v;
    }
#pragma unroll
    for (int j = 0; j < 6; ++j) {
      int idx = tid + j * 256;            // 0..1535
      int n = idx >> 3;
      int u = idx & 7;
      uint4 v = *reinterpret_cast<const uint4*>(ibf + ((size_t)(i0 * NREG_PAD + n)) * DIM + kk + (u << 3));
      *reinterpret_cast<uint4*>(&lds.st.B[n * 64 + ((u ^ (n & 7)) << 3)]) = v;
    }
    __syncthreads();
#pragma unroll
    for (int ks = 0; ks < 2; ++ks) {
      const int ub = ks * 4 + quad;       // logical 16B-unit index within the row
      bf16x8 fa[4], fb[6];
#pragma unroll
      for (int mt = 0; mt < 4; ++mt) {
        const int r = aRow + mt * 16 + l15;
        fa[mt] = *reinterpret_cast<const bf16x8*>(&lds.st.A[r * 64 + ((ub ^ (r & 7)) << 3)]);
      }
#pragma unroll
      for (int nt = 0; nt < 6; ++nt) {
        const int r = bRow + nt * 16 + l15;
        fb[nt] = *reinterpret_cast<const bf16x8*>(&lds.st.B[r * 64 + ((ub ^ (r & 7)) << 3)]);
      }
#pragma unroll
      for (int mt = 0; mt < 4; ++mt)
#pragma unroll
        for (int nt = 0; nt < 6; ++nt)
          acc[mt][nt] = __builtin_amdgcn_mfma_f32_16x16x32_bf16(fa[mt], fb[nt], acc[mt][nt], 0, 0, 0);
    }
    __syncthreads();
  }

  // ---- epilogue ----
  // stage G' (bf16, swizzled) for the 4 images; zero attn buffers (K-pad 48..63 stays 0)
  for (int idx = tid; idx < 4 * 48 * 8; idx += 256) {      // 1536 16B units
    int img = idx / 384;
    int rem = idx - img * 384;
    int n = rem >> 3, u = rem & 7;
    uint4 v = *reinterpret_cast<const uint4*>(gbf + ((size_t)(i0 + img) * 48 + n) * 64 + (u << 3));
    *reinterpret_cast<uint4*>(&lds.ep.gp[img][n * 64 + ((u ^ (n & 7)) << 3)]) = v;
  }
  {
    const uint4 z4 = make_uint4(0, 0, 0, 0);
    uint4* ab = reinterpret_cast<uint4*>(&lds.ep.attn[0][0]);
    for (int idx = tid; idx < 2048; idx += 256) ab[idx] = z4;
  }
  __syncthreads();

  const int lo = l15 & 7, hi = l15 >> 3;

#pragma unroll
  for (int img = 0; img < 2; ++img) {
    const int gimg = wx * 2 + img;
    const float* dg = gdiag + (size_t)(i0 + gimg) * 48;
    const float d0 = dg[l15];
    const float d1 = dg[16 + l15];
    const float d2 = dg[32 + l15];
    // per-region l2 norm over w (C-layout: rows live across quads -> xor 16,32)
    float scale[3];
#pragma unroll
    for (int nt3 = 0; nt3 < 3; ++nt3) {
      const int nt = img * 3 + nt3;
      float p = 0.f;
#pragma unroll
      for (int mt = 0; mt < 4; ++mt)
#pragma unroll
        for (int rg = 0; rg < 4; ++rg) {
          float s = acc[mt][nt][rg];
          float l = s < 0.f ? 0.1f * s : s;
          p += l * l;
        }
      p += __shfl_xor(p, 16);
      p += __shfl_xor(p, 32);
      scale[nt3] = 9.0f / (sqrtf(p) + 1e-8f);   // SMOOTH folded in
    }
    const bool vr2 = (l15 < 4);   // r = 32+l15 valid only if < 36
    // softmax over r, w12, diag term, attn -> LDS (bf16, swizzled rows)
#pragma unroll
    for (int mt = 0; mt < 4; ++mt) {
#pragma unroll
      for (int rg = 0; rg < 4; ++rg) {
        const float s0 = acc[mt][img * 3 + 0][rg];
        const float s1 = acc[mt][img * 3 + 1][rg];
        const float s2 = acc[mt][img * 3 + 2][rg];
        const float t0 = (s0 < 0.f ? 0.1f * s0 : s0) * scale[0];
        const float t1 = (s1 < 0.f ? 0.1f * s1 : s1) * scale[1];
        const float t2 = (s2 < 0.f ? 0.1f * s2 : s2) * scale[2];
        float mx = fmaxf(t0, t1);
        if (vr2) mx = fmaxf(mx, t2);
        mx = fmaxf(mx, __shfl_xor(mx, 1));
        mx = fmaxf(mx, __shfl_xor(mx, 2));
        mx = fmaxf(mx, __shfl_xor(mx, 4));
        mx = fmaxf(mx, __shfl_xor(mx, 8));
        const float e0 = __expf(t0 - mx);
        const float e1 = __expf(t1 - mx);
        const float e2 = vr2 ? __expf(t2 - mx) : 0.f;
        float sm = e0 + e1 + e2;
        sm += __shfl_xor(sm, 1);
        sm += __shfl_xor(sm, 2);
        sm += __shfl_xor(sm, 4);
        sm += __shfl_xor(sm, 8);
        const float inv = 1.0f / sm;
        const float a0 = e0 * inv, a1 = e1 * inv, a2 = e2 * inv;   // a2==0 when invalid
        float wp = a0 * s0 + a1 * s1 + a2 * s2;                    // w12 uses RAW s
        float dd = a0 * a0 * d0 + a1 * a1 * d1 + a2 * a2 * d2;     // exact diag term
        wp += __shfl_xor(wp, 1); wp += __shfl_xor(wp, 2);
        wp += __shfl_xor(wp, 4); wp += __shfl_xor(wp, 8);
        dd += __shfl_xor(dd, 1); dd += __shfl_xor(dd, 2);
        dd += __shfl_xor(dd, 4); dd += __shfl_xor(dd, 8);
        const int w = mt * 16 + quad * 4 + rg;
        const int w7 = w & 7;
        unsigned short* arow = &lds.ep.attn[wv][w * 64];
        arow[(((0 + hi) ^ w7) << 3) + lo] = f2bf(a0);
        arow[(((2 + hi) ^ w7) << 3) + lo] = f2bf(a1);
        arow[(((4 + hi) ^ w7) << 3) + lo] = f2bf(a2);
        if (l15 == 0) { lds.ep.w12[wv][w] = wp; lds.ep.w2d[wv][w] = dd; }
      }
    }
    // Y = Attn x G' via MFMA (wave-private; in-wave lgkmcnt ordering suffices)
    bf16x8 gfrag[3][2];
#pragma unroll
    for (int nt = 0; nt < 3; ++nt)
#pragma unroll
      for (int ks = 0; ks < 2; ++ks) {
        const int n = nt * 16 + l15;
        gfrag[nt][ks] = *reinterpret_cast<const bf16x8*>(
            &lds.ep.gp[gimg][n * 64 + (((ks * 4 + quad) ^ (n & 7)) << 3)]);
      }
#pragma unroll
    for (int mt = 0; mt < 4; ++mt) {
      bf16x8 af[2];
#pragma unroll
      for (int ks = 0; ks < 2; ++ks)
        af[ks] = *reinterpret_cast<const bf16x8*>(
            &lds.ep.attn[wv][(mt * 16 + l15) * 64 + (((ks * 4 + quad) ^ (l15 & 7)) << 3)]);
      f32x4 Y[3] = {zero4, zero4, zero4};
#pragma unroll
      for (int nt = 0; nt < 3; ++nt)
#pragma unroll
        for (int ks = 0; ks < 2; ++ks)
          Y[nt] = __builtin_amdgcn_mfma_f32_16x16x32_bf16(af[ks], gfrag[nt][ks], Y[nt], 0, 0, 0);
      // cross term: w2x[w] = sum_{r'} a[w][r'] * Y[w][r']  (Y C-layout == a C-layout)
#pragma unroll
      for (int rg = 0; rg < 4; ++rg) {
        const int w = mt * 16 + quad * 4 + rg;
        const int w7 = w & 7;
        float p = 0.f;
#pragma unroll
        for (int nt = 0; nt < 3; ++nt) {
          const unsigned short b = lds.ep.attn[wv][w * 64 + (((nt * 2 + hi) ^ w7) << 3) + lo];
          p += __uint_as_float((unsigned)b << 16) * Y[nt][rg];
        }
        p += __shfl_xor(p, 1); p += __shfl_xor(p, 2);
        p += __shfl_xor(p, 4); p += __shfl_xor(p, 8);
        if (l15 == 0) lds.ep.w2x[wv][w] = p;
      }
    }
    // final: lane = word
    float simv = 0.f;
    if (lane < clen) {
      const float w2sq = fmaxf(lds.ep.w2x[wv][lane] + lds.ep.w2d[wv][lane], 0.f);
      const float w2v = sqrtf(w2sq);
      const float w12v = lds.ep.w12[wv][lane];
      const float w1v = w1[(size_t)c * WPAD + lane];
      simv = w12v / fmaxf(w1v * w2v, 1e-8f);
    }
    simv += __shfl_xor(simv, 1);
    simv += __shfl_xor(simv, 2);
    simv += __shfl_xor(simv, 4);
    simv += __shfl_xor(simv, 8);
    simv += __shfl_xor(simv, 16);
    simv += __shfl_xor(simv, 32);
    if (lane == 0) {
      const int i = i0 + wx * 2 + img;
      out[(size_t)i * NCAP + c] = simv / (float)clen;
    }
  }
}

extern "C" void kernel_launch(void* const* d_in, const int* in_sizes, int n_in,
                              void* d_out, int out_size, void* d_ws, size_t ws_size,
                              hipStream_t stream) {
  const float* imgs = (const float*)d_in[0];
  const float* caps = (const float*)d_in[1];
  const int* cap_lens = (const int*)d_in[3];   // img_lens (d_in[2]) unused by reference
  float* out = (float*)d_out;

  char* ws = (char*)d_ws;
  const size_t QBF_B = (size_t)NCAP * WPAD * DIM * 2;        // 33,554,432
  const size_t IBF_B = (size_t)NIMG * NREG_PAD * DIM * 2;    // 25,165,824
  const size_t W1_B = (size_t)NCAP * WPAD * 4;               // 65,536
  const size_t GBF_B = (size_t)NIMG * 48 * 64 * 2;           // 1,572,864
  unsigned short* qbf = (unsigned short*)ws;
  unsigned short* ibf = (unsigned short*)(ws + QBF_B);
  float* w1 = (float*)(ws + QBF_B + IBF_B);
  unsigned short* gbf = (unsigned short*)(ws + QBF_B + IBF_B + W1_B);
  float* gdiag = (float*)(ws + QBF_B + IBF_B + W1_B + GBF_B);   // +49,152 -> ~57.6 MiB total

  k_prep_caps<<<NCAP * WPAD, 256, 0, stream>>>(caps, cap_lens, qbf, w1);
  k_prep_imgs<<<NIMG * NREG_PAD, 256, 0, stream>>>(imgs, ibf);
  k_gram<<<NIMG, 256, 0, stream>>>(imgs, gbf, gdiag);
  k_main<<<dim3(NIMG / 4, NCAP / 2), 256, 0, stream>>>(qbf, ibf, w1, gbf, gdiag, cap_lens, out);
}